// Round 3
// baseline (1030.979 us; speedup 1.0000x reference)
//
#include <hip/hip_runtime.h>
#include <math.h>

#define B_PTS   262144
#define NLEV    16
#define MASK4   ((1u << 22) - 1u)
#define MASK3   ((1u << 15) - 1u)
#define P1      2654435761u
#define P2      805459861u
#define P3      3674653429u

struct LevelParams {
    float res[NLEV];
    float rest[NLEV];
};

// One thread per (point, level). PPB points per 256-thread block, 256/PPB
// levels per block (levels [L0, L0 + 256/PPB)). Packing a point's levels in
// one block puts its partial output-row writes on one XCD's L2 -> merged
// writeback. Level-group footprint (sum of 4D tables) <= 134 MB << 256 MB L3,
// so within-launch inter-block drift cannot evict the active slices: every
// line's ~8 reuses are L3 hits and HBM traffic stays compulsory.
template<int L0, int PPB, int WRITE_KEEP>
__global__ __launch_bounds__(256)
void embed_levels(const float4* __restrict__ x,
                  const float2* __restrict__ emb4d,
                  const float2* __restrict__ emb3d,
                  float* __restrict__ out,
                  float* __restrict__ keep,
                  LevelParams lp)
{
    const int t   = threadIdx.x;
    const int p   = blockIdx.x * PPB + (t & (PPB - 1));
    const int lev = L0 + t / PPB;

    const float4 xv = x[p];
    const float xd[4] = { xv.x, xv.y, xv.z, xv.w };
    const float R  = lp.res[lev];
    const float Rt = lp.rest[lev];
    const float resv[4] = { R, R, R, Rt };

    uint32_t tt[4][2];
    float w0[4], w1[4];
    #pragma unroll
    for (int d = 0; d < 4; ++d) {
        // exact op sequence of the reference (f32 throughout)
        float grid = 1.0f / resv[d];
        float xc   = fminf(fmaxf(xd[d], 0.0f), 1.0f);
        float bl   = floorf(xc / grid);
        float vmin = bl * grid;
        float w    = (xd[d] - vmin) / grid;
        int bi     = (int)bl;
        uint32_t prime = (d == 0) ? 1u : (d == 1) ? P1 : (d == 2) ? P2 : P3;
        tt[d][0] = (uint32_t)bi * prime;
        tt[d][1] = (uint32_t)(bi + 1) * prime;
        w1[d] = w;
        w0[d] = 1.0f - w;
    }

    // all 24 gathers issued back-to-back: full memory-level parallelism
    const float2* tab4 = emb4d + ((size_t)lev << 22);
    const float2* tab3 = emb3d + ((size_t)lev << 15);
    float2 v4[16], v3[8];
    #pragma unroll
    for (int c = 0; c < 16; ++c) {
        uint32_t h = (tt[0][(c >> 3) & 1] ^ tt[1][(c >> 2) & 1] ^
                      tt[2][(c >> 1) & 1] ^ tt[3][c & 1]) & MASK4;
        v4[c] = tab4[h];
    }
    #pragma unroll
    for (int c = 0; c < 8; ++c) {
        uint32_t h = (tt[0][(c >> 2) & 1] ^ tt[1][(c >> 1) & 1] ^
                      tt[2][c & 1]) & MASK3;
        v3[c] = tab3[h];
    }

    float ex = 0.0f, ey = 0.0f;
    #pragma unroll
    for (int c = 0; c < 16; ++c) {
        float wt = ((c & 8) ? w1[0] : w0[0]) * ((c & 4) ? w1[1] : w0[1]) *
                   ((c & 2) ? w1[2] : w0[2]) * ((c & 1) ? w1[3] : w0[3]);
        ex = fmaf(v4[c].x, wt, ex);
        ey = fmaf(v4[c].y, wt, ey);
    }
    #pragma unroll
    for (int c = 0; c < 8; ++c) {
        float wt = ((c & 4) ? w1[0] : w0[0]) * ((c & 2) ? w1[1] : w0[1]) *
                   ((c & 1) ? w1[2] : w0[2]);
        ex = fmaf(v3[c].x, wt, ex);
        ey = fmaf(v3[c].y, wt, ey);
    }

    *reinterpret_cast<float2*>(out + (size_t)p * 32 + 2 * lev) = make_float2(ex, ey);

    if (WRITE_KEEP && t < PPB) {
        bool k4 = (xv.x >= 0.0f) && (xv.x <= 1.0f) &&
                  (xv.y >= 0.0f) && (xv.y <= 1.0f) &&
                  (xv.z >= 0.0f) && (xv.z <= 1.0f) &&
                  (xv.w >= 0.0f) && (xv.w <= 1.0f);
        keep[p] = k4 ? 1.0f : 0.0f;
    }
}

extern "C" void kernel_launch(void* const* d_in, const int* in_sizes, int n_in,
                              void* d_out, int out_size, void* d_ws, size_t ws_size,
                              hipStream_t stream)
{
    const float4* x     = (const float4*)d_in[0];
    const float2* emb4d = (const float2*)d_in[1];
    const float2* emb3d = (const float2*)d_in[2];
    float* out  = (float*)d_out;
    float* keep = out + (size_t)B_PTS * 32;

    // Replicate numpy's double-precision level-resolution computation exactly
    // (values sit on floor() boundaries: 16*b^3 ~= 32.0, 2*bt^15 ~= 32.0).
    LevelParams lp;
    const double b  = exp((log(512.0) - log(16.0)) / 15.0);
    const double bt = exp((log(32.0)  - log(2.0))  / 15.0);
    for (int i = 0; i < NLEV; ++i) {
        lp.res[i]  = (float)floor(16.0 * pow(b,  (double)i));
        lp.rest[i] = (float)floor(2.0  * pow(bt, (double)i));
    }

    // Launch boundaries = global barriers: each level group's table footprint
    // fits the 256 MB L3, so per-line reuse is captured and HBM traffic is
    // compulsory only.
    // levels 0-7  (~125 MB touched): 32 points x 8 levels per block
    embed_levels<0, 32, 1><<<B_PTS / 32, 256, 0, stream>>>(x, emb4d, emb3d, out, keep, lp);
    // levels 8-11 (134 MB): 64 points x 4 levels per block
    embed_levels<8, 64, 0><<<B_PTS / 64, 256, 0, stream>>>(x, emb4d, emb3d, out, keep, lp);
    // levels 12-15 (134 MB)
    embed_levels<12, 64, 0><<<B_PTS / 64, 256, 0, stream>>>(x, emb4d, emb3d, out, keep, lp);
}

// Round 4
// 753.094 us; speedup vs baseline: 1.3690x; 1.3690x over previous
//
#include <hip/hip_runtime.h>
#include <math.h>

#define B_PTS   262144
#define NLEV    16
#define MASK4   ((1u << 22) - 1u)
#define MASK3   ((1u << 15) - 1u)
#define P1      2654435761u
#define P2      805459861u
#define P3      3674653429u

struct LevelParams {
    float res[NLEV];
    float rest[NLEV];
};

// Block = 16 points x 16 levels (one thread per (point, level)).
// - All 16 levels of a point live in one block -> its 128 B output row is
//   staged in LDS and written with ONE coalesced block store (write amp 4x->1x).
// - PRIMES[0]==1 => corners i=0/1 (same j,k,l) hash to adjacent entries
//   {2m, 2m+1} whenever bl0 is even: one float4 load covers both. Odd bl0
//   needs one extra float2 load. Avg 12 requests/thread instead of 16+8.
__global__ __launch_bounds__(256)
void embed_all(const float4* __restrict__ x,
               const float2* __restrict__ emb4d,
               const float2* __restrict__ emb3d,
               float* __restrict__ out,
               float* __restrict__ keep,
               LevelParams lp)
{
    __shared__ float tile[16 * 33];   // [point][32 cols], +1 pad

    const int t     = threadIdx.x;
    const int pl    = t & 15;
    const int lev   = t >> 4;
    const int pbase = blockIdx.x * 16;

    const float4 xv = x[pbase + pl];
    const float xd[4] = { xv.x, xv.y, xv.z, xv.w };
    const float R  = lp.res[lev];
    const float Rt = lp.rest[lev];
    const float resv[4] = { R, R, R, Rt };

    uint32_t tt[4][2];
    float w0[4], w1[4];
    #pragma unroll
    for (int d = 0; d < 4; ++d) {
        // exact op sequence of the reference (f32 throughout)
        float grid = 1.0f / resv[d];
        float xc   = fminf(fmaxf(xd[d], 0.0f), 1.0f);
        float bl   = floorf(xc / grid);
        float vmin = bl * grid;
        float w    = (xd[d] - vmin) / grid;
        int bi     = (int)bl;
        uint32_t prime = (d == 0) ? 1u : (d == 1) ? P1 : (d == 2) ? P2 : P3;
        tt[d][0] = (uint32_t)bi * prime;
        tt[d][1] = (uint32_t)(bi + 1) * prime;
        w1[d] = w;
        w0[d] = 1.0f - w;
    }

    const uint32_t a   = tt[0][0];      // bl0 (prime 1)
    const bool     odd = (a & 1u) != 0u;
    const float    wx0 = w0[0], wx1 = w1[0];

    float ex = 0.0f, ey = 0.0f;

    // ---- 4D: 8 (j,k,l) combos, dim-0 pair per combo ----
    {
        const float2* tab4 = emb4d + ((size_t)lev << 22);
        #pragma unroll
        for (int c = 0; c < 8; ++c) {
            uint32_t E  = tt[1][(c >> 2) & 1] ^ tt[2][(c >> 1) & 1] ^ tt[3][c & 1];
            uint32_t h0 = (E ^ a) & MASK4;
            float4 q = *reinterpret_cast<const float4*>(tab4 + (h0 & ~1u));
            float2 e1;
            if (odd) e1 = tab4[(E ^ (a + 1u)) & MASK4];
            bool hi = (h0 & 1u) != 0u;
            float2 e0 = hi ? make_float2(q.z, q.w) : make_float2(q.x, q.y);
            if (!odd) e1 = hi ? make_float2(q.x, q.y) : make_float2(q.z, q.w);
            float wc = ((c & 4) ? w1[1] : w0[1]) *
                       ((c & 2) ? w1[2] : w0[2]) *
                       ((c & 1) ? w1[3] : w0[3]);
            ex = fmaf(fmaf(e0.x, wx0, e1.x * wx1), wc, ex);
            ey = fmaf(fmaf(e0.y, wx0, e1.y * wx1), wc, ey);
        }
    }

    // ---- 3D: 4 (j,k) combos, dim-0 pair per combo (L2-resident tables) ----
    {
        const float2* tab3 = emb3d + ((size_t)lev << 15);
        #pragma unroll
        for (int c = 0; c < 4; ++c) {
            uint32_t E  = tt[1][(c >> 1) & 1] ^ tt[2][c & 1];
            uint32_t h0 = (E ^ a) & MASK3;
            float4 q = *reinterpret_cast<const float4*>(tab3 + (h0 & ~1u));
            float2 e1;
            if (odd) e1 = tab3[(E ^ (a + 1u)) & MASK3];
            bool hi = (h0 & 1u) != 0u;
            float2 e0 = hi ? make_float2(q.z, q.w) : make_float2(q.x, q.y);
            if (!odd) e1 = hi ? make_float2(q.x, q.y) : make_float2(q.z, q.w);
            float wc = ((c & 2) ? w1[1] : w0[1]) *
                       ((c & 1) ? w1[2] : w0[2]);
            ex = fmaf(fmaf(e0.x, wx0, e1.x * wx1), wc, ex);
            ey = fmaf(fmaf(e0.y, wx0, e1.y * wx1), wc, ey);
        }
    }

    tile[pl * 33 + 2 * lev]     = ex;
    tile[pl * 33 + 2 * lev + 1] = ey;
    __syncthreads();

    // one coalesced 2 KB store: 256 threads x float2, consecutive addresses
    {
        int pw = t >> 4;              // point whose row-chunk this lane writes
        int cw = (2 * t) & 31;        // column
        float2 v = make_float2(tile[pw * 33 + cw], tile[pw * 33 + cw + 1]);
        *reinterpret_cast<float2*>(out + (size_t)pbase * 32 + 2 * t) = v;
    }

    if (t < 16) {
        const float4 xk = x[pbase + t];   // L1 hit
        bool k4 = (xk.x >= 0.0f) && (xk.x <= 1.0f) &&
                  (xk.y >= 0.0f) && (xk.y <= 1.0f) &&
                  (xk.z >= 0.0f) && (xk.z <= 1.0f) &&
                  (xk.w >= 0.0f) && (xk.w <= 1.0f);
        keep[pbase + t] = k4 ? 1.0f : 0.0f;
    }
}

extern "C" void kernel_launch(void* const* d_in, const int* in_sizes, int n_in,
                              void* d_out, int out_size, void* d_ws, size_t ws_size,
                              hipStream_t stream)
{
    const float4* x     = (const float4*)d_in[0];
    const float2* emb4d = (const float2*)d_in[1];
    const float2* emb3d = (const float2*)d_in[2];
    float* out  = (float*)d_out;
    float* keep = out + (size_t)B_PTS * 32;

    // Replicate numpy's double-precision level-resolution computation exactly
    // (values sit on floor() boundaries: 16*b^3 ~= 32.0, 2*bt^15 ~= 32.0).
    LevelParams lp;
    const double b  = exp((log(512.0) - log(16.0)) / 15.0);
    const double bt = exp((log(32.0)  - log(2.0))  / 15.0);
    for (int i = 0; i < NLEV; ++i) {
        lp.res[i]  = (float)floor(16.0 * pow(b,  (double)i));
        lp.rest[i] = (float)floor(2.0  * pow(bt, (double)i));
    }

    embed_all<<<B_PTS / 16, 256, 0, stream>>>(x, emb4d, emb3d, out, keep, lp);
}

// Round 5
// 671.256 us; speedup vs baseline: 1.5359x; 1.1219x over previous
//
#include <hip/hip_runtime.h>
#include <math.h>
#include <stdint.h>

#define B_PTS   262144
#define NLEV    16
#define MASK4   ((1u << 22) - 1u)
#define MASK3   ((1u << 15) - 1u)
#define P1      2654435761u
#define P2      805459861u
#define P3      3674653429u

#define LSH     3                // first XCD-sharded level
#define NSHL    (NLEV - LSH)     // 13 sharded levels
#define NCHUNK  256              // point chunks per level (1024 pts/chunk)

typedef float f32x4 __attribute__((ext_vector_type(4)));

struct LevelParams {
    float res[NLEV];
    float rest[NLEV];
};

struct PtState {
    uint32_t a;                          // bl0 * PRIMES[0](=1)
    uint32_t t1e, t1o, t2e, t2o, t3e, t3o;
    float w0, w1, w2, w3;                // lerp weight per dim (w1-side)
};

__device__ inline PtState mk_state(float xx, float xy, float xz, float xw,
                                   float R, float Rt)
{
    PtState st;
    const float xd[4] = { xx, xy, xz, xw };
    const float rv[4] = { R, R, R, Rt };
    uint32_t tt[4][2]; float ww[4];
    #pragma unroll
    for (int d = 0; d < 4; ++d) {
        // exact op sequence of the reference (f32 throughout)
        float grid = 1.0f / rv[d];
        float xc   = fminf(fmaxf(xd[d], 0.0f), 1.0f);
        float bl   = floorf(xc / grid);
        float vmin = bl * grid;
        float w    = (xd[d] - vmin) / grid;
        int bi     = (int)bl;
        uint32_t prime = (d == 0) ? 1u : (d == 1) ? P1 : (d == 2) ? P2 : P3;
        tt[d][0] = (uint32_t)bi * prime;
        tt[d][1] = (uint32_t)(bi + 1) * prime;
        ww[d] = w;
    }
    st.a   = tt[0][0];
    st.t1e = tt[1][0]; st.t1o = tt[1][1];
    st.t2e = tt[2][0]; st.t2o = tt[2][1];
    st.t3e = tt[3][0]; st.t3o = tt[3][1];
    st.w0 = ww[0]; st.w1 = ww[1]; st.w2 = ww[2]; st.w3 = ww[3];
    return st;
}

// round-to-nearest f32 -> bf16 (tolerance 2e-2 vs values ~1e-4: err ~1e-7)
__device__ inline uint32_t bfr(float v) {
    uint32_t u = __float_as_uint(v);
    u += 0x7FFFu + ((u >> 16) & 1u);
    return u >> 16;
}

// ---------------- K_low: 3D (all levels, level-separated) + 4D levels 0..2 --
__global__ __launch_bounds__(256)
void k_low(const float4* __restrict__ x,
           const float2* __restrict__ emb4d,
           const float2* __restrict__ emb3d,
           float2* __restrict__ wsA, LevelParams lp)
{
    const int p   = blockIdx.x * 256 + threadIdx.x;
    const int lev = blockIdx.y;

    const float4 xv = x[p];
    PtState st = mk_state(xv.x, xv.y, xv.z, xv.w, lp.res[lev], lp.rest[lev]);
    const uint32_t a = st.a;
    const bool odd = (a & 1u) != 0u;
    const float wx0 = 1.0f - st.w0, wx1 = st.w0;

    float ex = 0.0f, ey = 0.0f;

    // 3D: 4 (j,k) combos, dim-0 pair trick (PRIMES[0]==1 -> adjacent entries)
    {
        const float2* tab3 = emb3d + ((size_t)lev << 15);
        #pragma unroll
        for (int c = 0; c < 4; ++c) {
            uint32_t E  = ((c & 2) ? st.t1o : st.t1e) ^ ((c & 1) ? st.t2o : st.t2e);
            float   wc  = ((c & 2) ? st.w1 : (1.0f - st.w1)) *
                          ((c & 1) ? st.w2 : (1.0f - st.w2));
            uint32_t h0 = (E ^ a) & MASK3;
            if (!odd) {
                float4 q = *reinterpret_cast<const float4*>(tab3 + (h0 & ~1u));
                bool hi = (h0 & 1u) != 0u;
                float e0x = hi ? q.z : q.x, e0y = hi ? q.w : q.y;
                float e1x = hi ? q.x : q.z, e1y = hi ? q.y : q.w;
                ex = fmaf(fmaf(e0x, wx0, e1x * wx1), wc, ex);
                ey = fmaf(fmaf(e0y, wx0, e1y * wx1), wc, ey);
            } else {
                float2 e0 = tab3[h0];
                float2 e1 = tab3[(E ^ (a + 1u)) & MASK3];
                ex = fmaf(fmaf(e0.x, wx0, e1.x * wx1), wc, ex);
                ey = fmaf(fmaf(e0.y, wx0, e1.y * wx1), wc, ey);
            }
        }
    }

    // 4D for small levels only (cache-friendly footprints)
    if (lev < LSH) {
        const float2* tab4 = emb4d + ((size_t)lev << 22);
        #pragma unroll
        for (int c = 0; c < 8; ++c) {
            uint32_t E = ((c & 4) ? st.t1o : st.t1e) ^
                         ((c & 2) ? st.t2o : st.t2e) ^
                         ((c & 1) ? st.t3o : st.t3e);
            float wc = ((c & 4) ? st.w1 : (1.0f - st.w1)) *
                       ((c & 2) ? st.w2 : (1.0f - st.w2)) *
                       ((c & 1) ? st.w3 : (1.0f - st.w3));
            uint32_t h0 = (E ^ a) & MASK4;
            if (!odd) {
                float4 q = *reinterpret_cast<const float4*>(tab4 + (h0 & ~1u));
                bool hi = (h0 & 1u) != 0u;
                float e0x = hi ? q.z : q.x, e0y = hi ? q.w : q.y;
                float e1x = hi ? q.x : q.z, e1y = hi ? q.y : q.w;
                ex = fmaf(fmaf(e0x, wx0, e1x * wx1), wc, ex);
                ey = fmaf(fmaf(e0y, wx0, e1y * wx1), wc, ey);
            } else {
                float2 e0 = tab4[h0];
                float2 e1 = tab4[(E ^ (a + 1u)) & MASK4];
                ex = fmaf(fmaf(e0.x, wx0, e1.x * wx1), wc, ex);
                ey = fmaf(fmaf(e0.y, wx0, e1.y * wx1), wc, ey);
            }
        }
    }

    wsA[(size_t)lev * B_PTS + p] = make_float2(ex, ey);   // coalesced
}

// ---------------- K_shard: 4D levels LSH..15, XCD-sharded hash space --------
// bid = ((levi*NCHUNK + chunk)*8 + s): round-robin dispatch puts all blocks of
// shard s on XCD s; the contiguous 4.19 MB table slice [s<<19,(s+1)<<19) stays
// resident in that XCD's L2 while all points stream through.
__global__ __launch_bounds__(256)
void k_shard(const float4* __restrict__ x,
             const float2* __restrict__ emb4d,
             uint32_t* __restrict__ ws2, LevelParams lp)
{
    const int bid   = blockIdx.x;
    const int s     = bid & 7;
    const int rest  = bid >> 3;
    const int chunk = rest & (NCHUNK - 1);
    const int levi  = rest >> 8;           // log2(NCHUNK) = 8
    const int lev   = LSH + levi;
    const uint32_t slo = (uint32_t)s << 19;

    const float2* tab4 = emb4d + ((size_t)lev << 22);
    const float R = lp.res[lev], Rt = lp.rest[lev];
    const int pbase = chunk * 1024 + threadIdx.x;

    PtState st[4];
    float acx[4], acy[4];
    #pragma unroll
    for (int i = 0; i < 4; ++i) {
        // non-temporal: don't evict the L2-resident table slice
        f32x4 xv = __builtin_nontemporal_load(
            reinterpret_cast<const f32x4*>(&x[pbase + i * 256]));
        st[i] = mk_state(xv.x, xv.y, xv.z, xv.w, R, Rt);
        acx[i] = 0.0f; acy[i] = 0.0f;
    }

    #pragma unroll
    for (int i = 0; i < 4; ++i) {
        const uint32_t a = st[i].a;
        const bool odd = (a & 1u) != 0u;
        const float wx0 = 1.0f - st[i].w0, wx1 = st[i].w0;
        #pragma unroll
        for (int c = 0; c < 8; ++c) {
            uint32_t E = ((c & 4) ? st[i].t1o : st[i].t1e) ^
                         ((c & 2) ? st[i].t2o : st[i].t2e) ^
                         ((c & 1) ? st[i].t3o : st[i].t3e);
            float wc = ((c & 4) ? st[i].w1 : (1.0f - st[i].w1)) *
                       ((c & 2) ? st[i].w2 : (1.0f - st[i].w2)) *
                       ((c & 1) ? st[i].w3 : (1.0f - st[i].w3));
            uint32_t h0 = (E ^ a) & MASK4;
            if (!odd) {
                // even bl0: corners i=0/1 are entries {2m,2m+1}, same shard
                if ((h0 & 0x00380000u) == slo) {
                    float4 q = *reinterpret_cast<const float4*>(tab4 + (h0 & ~1u));
                    bool hi = (h0 & 1u) != 0u;
                    float e0x = hi ? q.z : q.x, e0y = hi ? q.w : q.y;
                    float e1x = hi ? q.x : q.z, e1y = hi ? q.y : q.w;
                    acx[i] = fmaf(fmaf(e0x, wx0, e1x * wx1), wc, acx[i]);
                    acy[i] = fmaf(fmaf(e0y, wx0, e1y * wx1), wc, acy[i]);
                }
            } else {
                if ((h0 & 0x00380000u) == slo) {
                    float2 e0 = tab4[h0];
                    acx[i] = fmaf(e0.x * wx0, wc, acx[i]);
                    acy[i] = fmaf(e0.y * wx0, wc, acy[i]);
                }
                uint32_t h1 = (E ^ (a + 1u)) & MASK4;
                if ((h1 & 0x00380000u) == slo) {
                    float2 e1 = tab4[h1];
                    acx[i] = fmaf(e1.x * wx1, wc, acx[i]);
                    acy[i] = fmaf(e1.y * wx1, wc, acy[i]);
                }
            }
        }
    }

    uint32_t* dst = ws2 + (size_t)(levi * 8 + s) * B_PTS + pbase;
    #pragma unroll
    for (int i = 0; i < 4; ++i) {
        uint32_t pk = bfr(acx[i]) | (bfr(acy[i]) << 16);
        __builtin_nontemporal_store(pk, dst + i * 256);   // coalesced
    }
}

// ---------------- K_final: reduce shards + transpose to out + keep ----------
__global__ __launch_bounds__(256)
void k_final(const float4* __restrict__ x,
             const float2* __restrict__ wsA,
             const uint32_t* __restrict__ ws2,
             float* __restrict__ out, float* __restrict__ keep)
{
    __shared__ float tile[256 * 33];
    const int t = threadIdx.x;
    const int p = blockIdx.x * 256 + t;

    float ax[NLEV], ay[NLEV];
    #pragma unroll
    for (int l = 0; l < NLEV; ++l) {
        float2 v = wsA[(size_t)l * B_PTS + p];       // coalesced
        ax[l] = v.x; ay[l] = v.y;
    }
    #pragma unroll
    for (int li = 0; li < NSHL; ++li) {
        #pragma unroll
        for (int s2 = 0; s2 < 8; ++s2) {
            uint32_t w = ws2[(size_t)(li * 8 + s2) * B_PTS + p];  // coalesced
            ax[LSH + li] += __uint_as_float(w << 16);
            ay[LSH + li] += __uint_as_float(w & 0xFFFF0000u);
        }
    }
    #pragma unroll
    for (int l = 0; l < NLEV; ++l) {
        tile[t * 33 + 2 * l]     = ax[l];
        tile[t * 33 + 2 * l + 1] = ay[l];
    }
    __syncthreads();

    float* ob = out + (size_t)blockIdx.x * (256 * 32);
    #pragma unroll
    for (int k = 0; k < 32; ++k) {
        int idx = k * 256 + t;
        ob[idx] = tile[(idx >> 5) * 33 + (idx & 31)];    // coalesced
    }

    const float4 xv = x[p];
    bool k4 = (xv.x >= 0.0f) && (xv.x <= 1.0f) &&
              (xv.y >= 0.0f) && (xv.y <= 1.0f) &&
              (xv.z >= 0.0f) && (xv.z <= 1.0f) &&
              (xv.w >= 0.0f) && (xv.w <= 1.0f);
    keep[p] = k4 ? 1.0f : 0.0f;
}

// ---------------- fallback (R4 monolithic) if ws is too small ---------------
__global__ __launch_bounds__(256)
void embed_all(const float4* __restrict__ x,
               const float2* __restrict__ emb4d,
               const float2* __restrict__ emb3d,
               float* __restrict__ out,
               float* __restrict__ keep,
               LevelParams lp)
{
    __shared__ float tile[16 * 33];
    const int t = threadIdx.x;
    const int pl = t & 15;
    const int lev = t >> 4;
    const int pbase = blockIdx.x * 16;

    const float4 xv = x[pbase + pl];
    PtState st = mk_state(xv.x, xv.y, xv.z, xv.w, lp.res[lev], lp.rest[lev]);
    const uint32_t a = st.a;
    const bool odd = (a & 1u) != 0u;
    const float wx0 = 1.0f - st.w0, wx1 = st.w0;
    float ex = 0.0f, ey = 0.0f;

    const float2* tab4 = emb4d + ((size_t)lev << 22);
    #pragma unroll
    for (int c = 0; c < 8; ++c) {
        uint32_t E = ((c & 4) ? st.t1o : st.t1e) ^ ((c & 2) ? st.t2o : st.t2e) ^
                     ((c & 1) ? st.t3o : st.t3e);
        float wc = ((c & 4) ? st.w1 : (1.0f - st.w1)) *
                   ((c & 2) ? st.w2 : (1.0f - st.w2)) *
                   ((c & 1) ? st.w3 : (1.0f - st.w3));
        uint32_t h0 = (E ^ a) & MASK4;
        float4 q = *reinterpret_cast<const float4*>(tab4 + (h0 & ~1u));
        float2 e1;
        if (odd) e1 = tab4[(E ^ (a + 1u)) & MASK4];
        bool hi = (h0 & 1u) != 0u;
        float2 e0 = hi ? make_float2(q.z, q.w) : make_float2(q.x, q.y);
        if (!odd) e1 = hi ? make_float2(q.x, q.y) : make_float2(q.z, q.w);
        ex = fmaf(fmaf(e0.x, wx0, e1.x * wx1), wc, ex);
        ey = fmaf(fmaf(e0.y, wx0, e1.y * wx1), wc, ey);
    }
    const float2* tab3 = emb3d + ((size_t)lev << 15);
    #pragma unroll
    for (int c = 0; c < 4; ++c) {
        uint32_t E = ((c & 2) ? st.t1o : st.t1e) ^ ((c & 1) ? st.t2o : st.t2e);
        float wc = ((c & 2) ? st.w1 : (1.0f - st.w1)) *
                   ((c & 1) ? st.w2 : (1.0f - st.w2));
        uint32_t h0 = (E ^ a) & MASK3;
        float4 q = *reinterpret_cast<const float4*>(tab3 + (h0 & ~1u));
        float2 e1;
        if (odd) e1 = tab3[(E ^ (a + 1u)) & MASK3];
        bool hi = (h0 & 1u) != 0u;
        float2 e0 = hi ? make_float2(q.z, q.w) : make_float2(q.x, q.y);
        if (!odd) e1 = hi ? make_float2(q.x, q.y) : make_float2(q.z, q.w);
        ex = fmaf(fmaf(e0.x, wx0, e1.x * wx1), wc, ex);
        ey = fmaf(fmaf(e0.y, wx0, e1.y * wx1), wc, ey);
    }

    tile[pl * 33 + 2 * lev]     = ex;
    tile[pl * 33 + 2 * lev + 1] = ey;
    __syncthreads();
    {
        int pw = t >> 4;
        int cw = (2 * t) & 31;
        float2 v = make_float2(tile[pw * 33 + cw], tile[pw * 33 + cw + 1]);
        *reinterpret_cast<float2*>(out + (size_t)pbase * 32 + 2 * t) = v;
    }
    if (t < 16) {
        const float4 xk = x[pbase + t];
        bool k4 = (xk.x >= 0.0f) && (xk.x <= 1.0f) &&
                  (xk.y >= 0.0f) && (xk.y <= 1.0f) &&
                  (xk.z >= 0.0f) && (xk.z <= 1.0f) &&
                  (xk.w >= 0.0f) && (xk.w <= 1.0f);
        keep[pbase + t] = k4 ? 1.0f : 0.0f;
    }
}

extern "C" void kernel_launch(void* const* d_in, const int* in_sizes, int n_in,
                              void* d_out, int out_size, void* d_ws, size_t ws_size,
                              hipStream_t stream)
{
    const float4* x     = (const float4*)d_in[0];
    const float2* emb4d = (const float2*)d_in[1];
    const float2* emb3d = (const float2*)d_in[2];
    float* out  = (float*)d_out;
    float* keep = out + (size_t)B_PTS * 32;

    // Replicate numpy's double-precision level-resolution computation exactly.
    LevelParams lp;
    const double b  = exp((log(512.0) - log(16.0)) / 15.0);
    const double bt = exp((log(32.0)  - log(2.0))  / 15.0);
    for (int i = 0; i < NLEV; ++i) {
        lp.res[i]  = (float)floor(16.0 * pow(b,  (double)i));
        lp.rest[i] = (float)floor(2.0  * pow(bt, (double)i));
    }

    const size_t wsA_bytes = (size_t)NLEV * B_PTS * 8;          // 33.6 MB f32x2
    const size_t ws2_bytes = (size_t)NSHL * 8 * B_PTS * 4;      // 109 MB bf16x2

    if (ws_size >= wsA_bytes + ws2_bytes && d_ws != nullptr) {
        float2*   wsA = (float2*)d_ws;
        uint32_t* ws2 = (uint32_t*)((char*)d_ws + wsA_bytes);
        k_low  <<<dim3(B_PTS / 256, NLEV), 256, 0, stream>>>(x, emb4d, emb3d, wsA, lp);
        k_shard<<<NSHL * NCHUNK * 8,       256, 0, stream>>>(x, emb4d, ws2, lp);
        k_final<<<B_PTS / 256,             256, 0, stream>>>(x, wsA, ws2, out, keep);
    } else {
        embed_all<<<B_PTS / 16, 256, 0, stream>>>(x, emb4d, emb3d, out, keep, lp);
    }
}

// Round 6
// 483.683 us; speedup vs baseline: 2.1315x; 1.3878x over previous
//
#include <hip/hip_runtime.h>
#include <math.h>
#include <stdint.h>

#define B_PTS   262144
#define NLEV    16
#define MASK4   ((1u << 22) - 1u)
#define MASK3   ((1u << 15) - 1u)
#define P1      2654435761u
#define P2      805459861u
#define P3      3674653429u

#define LSH     3                // first XCD-sharded level
#define NSHL    (NLEV - LSH)     // 13 sharded levels
#define NCHUNK  256              // point chunks per level (1024 pts/chunk)

typedef float f32x4 __attribute__((ext_vector_type(4)));

struct LevelParams {
    float res[NLEV];
    float rest[NLEV];
};

struct PtState {
    uint32_t a;                          // bl0 * PRIMES[0](=1)
    uint32_t t1e, t1o, t2e, t2o, t3e, t3o;
    float w0, w1, w2, w3;
};

// Fast-math state: no divisions. bl = floor(xc*res), w = x*res - bl.
// Differs from the reference's div-based path only in ULP-edge cell flips,
// where the interpolant is continuous (shared lattice corner, same hash) ->
// error ~1e-11 vs 2e-2 tolerance.
__device__ inline PtState mk_fast(float xx, float xy, float xz, float xw,
                                  float R, float Rt)
{
    PtState st;
    const float xd[4] = { xx, xy, xz, xw };
    const float rv[4] = { R, R, R, Rt };
    uint32_t tt[4][2]; float ww[4];
    #pragma unroll
    for (int d = 0; d < 4; ++d) {
        float xc = fminf(fmaxf(xd[d], 0.0f), 1.0f);
        float bl = floorf(xc * rv[d]);
        float w  = fmaf(xd[d], rv[d], -bl);
        uint32_t bi = (uint32_t)(int)bl;
        uint32_t prime = (d == 0) ? 1u : (d == 1) ? P1 : (d == 2) ? P2 : P3;
        tt[d][0] = bi * prime;
        tt[d][1] = tt[d][0] + prime;
        ww[d] = w;
    }
    st.a   = tt[0][0];
    st.t1e = tt[1][0]; st.t1o = tt[1][1];
    st.t2e = tt[2][0]; st.t2o = tt[2][1];
    st.t3e = tt[3][0]; st.t3o = tt[3][1];
    st.w0 = ww[0]; st.w1 = ww[1]; st.w2 = ww[2]; st.w3 = ww[3];
    return st;
}

// round-to-nearest f32 -> bf16 (tolerance 2e-2 vs values ~1e-4: err ~1e-7)
__device__ inline uint32_t bfr(float v) {
    uint32_t u = __float_as_uint(v);
    u += 0x7FFFu + ((u >> 16) & 1u);
    return u >> 16;
}

// ---------------- K_shard: 4D levels LSH..15, XCD-sharded hash space --------
// bid = ((levi*NCHUNK + chunk)*8 + s): round-robin dispatch puts all blocks of
// shard s on XCD s; the contiguous 4.19 MB table slice [s<<19,(s+1)<<19) stays
// resident in that XCD's L2. Fully branchless corner scan: inactive corners
// load a fixed slice-base line (L1 hit) with weight 0.
__global__ __launch_bounds__(256)
void k_shard(const float4* __restrict__ x,
             const float2* __restrict__ emb4d,
             uint32_t* __restrict__ ws2, LevelParams lp)
{
    const int bid   = blockIdx.x;
    const int s     = bid & 7;
    const int rest  = bid >> 3;
    const int chunk = rest & (NCHUNK - 1);
    const int levi  = rest >> 8;           // log2(NCHUNK) = 8
    const int lev   = LSH + levi;
    const uint32_t sh    = (uint32_t)s;
    const uint32_t dummy = sh << 19;       // slice base entry (stays in L1)

    const float2* tab4 = emb4d + ((size_t)lev << 22);
    const float R = lp.res[lev], Rt = lp.rest[lev];
    const int pbase = chunk * 1024 + threadIdx.x;
    uint32_t* dst = ws2 + (size_t)(levi * 8 + s) * B_PTS + pbase;

    #pragma unroll
    for (int i = 0; i < 4; ++i) {          // serial points: minimal live state
        f32x4 xr = __builtin_nontemporal_load(
            reinterpret_cast<const f32x4*>(&x[pbase + i * 256]));
        PtState st = mk_fast(xr.x, xr.y, xr.z, xr.w, R, Rt);

        const float w1e = 1.0f - st.w1, w2e = 1.0f - st.w2, w3e = 1.0f - st.w3;
        const float q00 = w1e * w2e, q01 = w1e * st.w2,
                    q10 = st.w1 * w2e, q11 = st.w1 * st.w2;
        const float wc[8] = { q00 * w3e, q00 * st.w3, q01 * w3e, q01 * st.w3,
                              q10 * w3e, q10 * st.w3, q11 * w3e, q11 * st.w3 };
        const float wx0 = 1.0f - st.w0, wx1 = st.w0;
        const uint32_t a0 = st.a, a1 = st.a + 1u;

        float ex = 0.0f, ey = 0.0f;
        #pragma unroll
        for (int c = 0; c < 8; ++c) {
            const uint32_t E = ((c & 4) ? st.t1o : st.t1e) ^
                               ((c & 2) ? st.t2o : st.t2e) ^
                               ((c & 1) ? st.t3o : st.t3e);
            {   // corner i=0
                uint32_t h   = (E ^ a0) & MASK4;
                bool     act = (h >> 19) == sh;
                float2   v   = tab4[act ? h : dummy];
                float    wt  = act ? wx0 * wc[c] : 0.0f;
                ex = fmaf(v.x, wt, ex);
                ey = fmaf(v.y, wt, ey);
            }
            {   // corner i=1
                uint32_t h   = (E ^ a1) & MASK4;
                bool     act = (h >> 19) == sh;
                float2   v   = tab4[act ? h : dummy];
                float    wt  = act ? wx1 * wc[c] : 0.0f;
                ex = fmaf(v.x, wt, ex);
                ey = fmaf(v.y, wt, ey);
            }
        }

        uint32_t pk = bfr(ex) | (bfr(ey) << 16);
        __builtin_nontemporal_store(pk, dst + i * 256);   // coalesced
    }
}

// ---------------- K_final: 3D all levels + 4D levels 0..2 + shard reduce ----
__global__ __launch_bounds__(256)
void k_final(const float4* __restrict__ x,
             const float2* __restrict__ emb4d,
             const float2* __restrict__ emb3d,
             const uint32_t* __restrict__ ws2,
             float* __restrict__ out, float* __restrict__ keep,
             LevelParams lp)
{
    __shared__ float tile[256 * 33];
    const int t = threadIdx.x;
    const int p = blockIdx.x * 256 + t;

    const float4 xv = x[p];

    for (int lev = 0; lev < NLEV; ++lev) {
        PtState st = mk_fast(xv.x, xv.y, xv.z, xv.w, lp.res[lev], lp.rest[lev]);
        const uint32_t a0 = st.a, a1 = st.a + 1u;
        const float wx[2] = { 1.0f - st.w0, st.w0 };
        const float wy[2] = { 1.0f - st.w1, st.w1 };
        const float wz[2] = { 1.0f - st.w2, st.w2 };
        const float wwv[2] = { 1.0f - st.w3, st.w3 };

        float ex = 0.0f, ey = 0.0f;

        // shard partials for this level (coalesced u32 reads, bf16x2 packed)
        if (lev >= LSH) {
            const int li = lev - LSH;
            #pragma unroll
            for (int s2 = 0; s2 < 8; ++s2) {
                uint32_t w = ws2[(size_t)(li * 8 + s2) * B_PTS + p];
                ex += __uint_as_float(w << 16);
                ey += __uint_as_float(w & 0xFFFF0000u);
            }
        }

        // 3D: 8 corners, footprint <=256 KB/level (cache-resident)
        {
            const float2* tab3 = emb3d + ((size_t)lev << 15);
            #pragma unroll
            for (int c = 0; c < 8; ++c) {   // bit2=i(dim0) bit1=j bit0=k
                uint32_t E = ((c & 2) ? st.t1o : st.t1e) ^
                             ((c & 1) ? st.t2o : st.t2e);
                uint32_t h = (E ^ ((c & 4) ? a1 : a0)) & MASK3;
                float wt = wx[(c >> 2) & 1] * wy[(c >> 1) & 1] * wz[c & 1];
                float2 v = tab3[h];
                ex = fmaf(v.x, wt, ex);
                ey = fmaf(v.y, wt, ey);
            }
        }

        // 4D small levels: touched footprint 1-5 MB (L3-resident after sweep)
        if (lev < LSH) {
            const float2* tab4 = emb4d + ((size_t)lev << 22);
            #pragma unroll
            for (int c = 0; c < 16; ++c) {  // bit3=i bit2=j bit1=k bit0=l
                uint32_t E = ((c & 4) ? st.t1o : st.t1e) ^
                             ((c & 2) ? st.t2o : st.t2e) ^
                             ((c & 1) ? st.t3o : st.t3e);
                uint32_t h = (E ^ ((c & 8) ? a1 : a0)) & MASK4;
                float wt = wx[(c >> 3) & 1] * wy[(c >> 2) & 1] *
                           wz[(c >> 1) & 1] * wwv[c & 1];
                float2 v = tab4[h];
                ex = fmaf(v.x, wt, ex);
                ey = fmaf(v.y, wt, ey);
            }
        }

        tile[t * 33 + 2 * lev]     = ex;
        tile[t * 33 + 2 * lev + 1] = ey;
    }

    __syncthreads();

    float* ob = out + (size_t)blockIdx.x * (256 * 32);
    #pragma unroll
    for (int k = 0; k < 32; ++k) {
        int idx = k * 256 + t;
        ob[idx] = tile[(idx >> 5) * 33 + (idx & 31)];    // coalesced
    }

    bool k4 = (xv.x >= 0.0f) && (xv.x <= 1.0f) &&
              (xv.y >= 0.0f) && (xv.y <= 1.0f) &&
              (xv.z >= 0.0f) && (xv.z <= 1.0f) &&
              (xv.w >= 0.0f) && (xv.w <= 1.0f);
    keep[p] = k4 ? 1.0f : 0.0f;
}

// ---------------- fallback (monolithic) if ws is too small ------------------
__global__ __launch_bounds__(256)
void embed_all(const float4* __restrict__ x,
               const float2* __restrict__ emb4d,
               const float2* __restrict__ emb3d,
               float* __restrict__ out,
               float* __restrict__ keep,
               LevelParams lp)
{
    __shared__ float tile[16 * 33];
    const int t = threadIdx.x;
    const int pl = t & 15;
    const int lev = t >> 4;
    const int pbase = blockIdx.x * 16;

    const float4 xv = x[pbase + pl];
    PtState st = mk_fast(xv.x, xv.y, xv.z, xv.w, lp.res[lev], lp.rest[lev]);
    const uint32_t a0 = st.a, a1 = st.a + 1u;
    const float wx[2] = { 1.0f - st.w0, st.w0 };
    const float wy[2] = { 1.0f - st.w1, st.w1 };
    const float wz[2] = { 1.0f - st.w2, st.w2 };
    const float wwv[2] = { 1.0f - st.w3, st.w3 };
    float ex = 0.0f, ey = 0.0f;

    const float2* tab4 = emb4d + ((size_t)lev << 22);
    #pragma unroll
    for (int c = 0; c < 16; ++c) {
        uint32_t E = ((c & 4) ? st.t1o : st.t1e) ^ ((c & 2) ? st.t2o : st.t2e) ^
                     ((c & 1) ? st.t3o : st.t3e);
        uint32_t h = (E ^ ((c & 8) ? a1 : a0)) & MASK4;
        float wt = wx[(c >> 3) & 1] * wy[(c >> 2) & 1] *
                   wz[(c >> 1) & 1] * wwv[c & 1];
        float2 v = tab4[h];
        ex = fmaf(v.x, wt, ex);
        ey = fmaf(v.y, wt, ey);
    }
    const float2* tab3 = emb3d + ((size_t)lev << 15);
    #pragma unroll
    for (int c = 0; c < 8; ++c) {
        uint32_t E = ((c & 2) ? st.t1o : st.t1e) ^ ((c & 1) ? st.t2o : st.t2e);
        uint32_t h = (E ^ ((c & 4) ? a1 : a0)) & MASK3;
        float wt = wx[(c >> 2) & 1] * wy[(c >> 1) & 1] * wz[c & 1];
        float2 v = tab3[h];
        ex = fmaf(v.x, wt, ex);
        ey = fmaf(v.y, wt, ey);
    }

    tile[pl * 33 + 2 * lev]     = ex;
    tile[pl * 33 + 2 * lev + 1] = ey;
    __syncthreads();
    {
        int pw = t >> 4;
        int cw = (2 * t) & 31;
        float2 v = make_float2(tile[pw * 33 + cw], tile[pw * 33 + cw + 1]);
        *reinterpret_cast<float2*>(out + (size_t)pbase * 32 + 2 * t) = v;
    }
    if (t < 16) {
        const float4 xk = x[pbase + t];
        bool k4 = (xk.x >= 0.0f) && (xk.x <= 1.0f) &&
                  (xk.y >= 0.0f) && (xk.y <= 1.0f) &&
                  (xk.z >= 0.0f) && (xk.z <= 1.0f) &&
                  (xk.w >= 0.0f) && (xk.w <= 1.0f);
        keep[pbase + t] = k4 ? 1.0f : 0.0f;
    }
}

extern "C" void kernel_launch(void* const* d_in, const int* in_sizes, int n_in,
                              void* d_out, int out_size, void* d_ws, size_t ws_size,
                              hipStream_t stream)
{
    const float4* x     = (const float4*)d_in[0];
    const float2* emb4d = (const float2*)d_in[1];
    const float2* emb3d = (const float2*)d_in[2];
    float* out  = (float*)d_out;
    float* keep = out + (size_t)B_PTS * 32;

    // Replicate numpy's double-precision level-resolution computation exactly.
    LevelParams lp;
    const double b  = exp((log(512.0) - log(16.0)) / 15.0);
    const double bt = exp((log(32.0)  - log(2.0))  / 15.0);
    for (int i = 0; i < NLEV; ++i) {
        lp.res[i]  = (float)floor(16.0 * pow(b,  (double)i));
        lp.rest[i] = (float)floor(2.0  * pow(bt, (double)i));
    }

    const size_t ws2_bytes = (size_t)NSHL * 8 * B_PTS * 4;      // 109 MB bf16x2

    if (ws_size >= ws2_bytes && d_ws != nullptr) {
        uint32_t* ws2 = (uint32_t*)d_ws;
        k_shard<<<NSHL * NCHUNK * 8, 256, 0, stream>>>(x, emb4d, ws2, lp);
        k_final<<<B_PTS / 256,       256, 0, stream>>>(x, emb4d, emb3d, ws2,
                                                       out, keep, lp);
    } else {
        embed_all<<<B_PTS / 16, 256, 0, stream>>>(x, emb4d, emb3d, out, keep, lp);
    }
}